// Round 1
// baseline (164.389 us; speedup 1.0000x reference)
//
#include <hip/hip_runtime.h>
#include <math.h>

#define NN 2048   // nodes
#define IF 128    // in features
#define NH 4      // heads
#define NF 16     // hidden per head
#define OF 64     // NH*NF

// ---------------- Kernel 1: projections g_l = h@W_l, g_r = h@W_r ----------------
// grid (NN, 2), block 64. blockIdx.y selects W_l/W_r.
__global__ __launch_bounds__(64) void proj_kernel(const float* __restrict__ h,
                                                  const float* __restrict__ Wl,
                                                  const float* __restrict__ Wr,
                                                  float* __restrict__ gl,
                                                  float* __restrict__ gr) {
    const int i   = blockIdx.x;
    const int col = threadIdx.x;                 // 0..63 output column
    const float* W = (blockIdx.y == 0) ? Wl : Wr;
    float*       g = (blockIdx.y == 0) ? gl : gr;

    __shared__ float hs[IF];
    hs[col]      = h[i * IF + col];
    hs[col + 64] = h[i * IF + col + 64];
    __syncthreads();

    float acc = 0.f;
    #pragma unroll
    for (int k = 0; k < IF; ++k)
        acc = fmaf(hs[k], W[k * OF + col], acc);   // threads read consecutive cols: coalesced
    g[i * OF + col] = acc;
}

// ---------------- Kernel 2: per-node attention ----------------
// grid NN, block 256. One block = one target node i.
__global__ __launch_bounds__(256) void gat_kernel(const float* __restrict__ g_l,
                                                  const float* __restrict__ g_r,
                                                  const int*   __restrict__ adj,
                                                  const float* __restrict__ attn_w,
                                                  float*       __restrict__ out) {
    const int i = blockIdx.x;
    const int t = threadIdx.x;

    __shared__ float e_buf[NH][NN + 1];   // +1 pad: avoids 4-way bank conflict in PV phase
    __shared__ float gri[OF];
    __shared__ float aw[NF];
    __shared__ float red[256];

    if (t < OF) gri[t] = g_r[i * OF + t];
    if (t < NF) aw[t]  = attn_w[t];
    __syncthreads();

    // Registers: this node's target-side projection + attention vector
    float gr_r[OF];
    float aw_r[NF];
    #pragma unroll
    for (int c = 0; c < OF; ++c) gr_r[c] = gri[c];
    #pragma unroll
    for (int f = 0; f < NF; ++f) aw_r[f] = aw[f];

    // ---- Phase A: e[i,j,h] for all j, with adjacency masking ----
    #pragma unroll
    for (int jj = 0; jj < NN / 256; ++jj) {
        const int j = t + jj * 256;
        const float4* glr = (const float4*)(g_l + j * OF);
        const int m = adj[i * NN + j];
        float e[NH] = {0.f, 0.f, 0.f, 0.f};
        #pragma unroll
        for (int q = 0; q < 16; ++q) {          // q indexes float4 chunks of the 64-wide row
            const float4 v = glr[q];
            const int hh = q >> 2;
            const int f0 = (q & 3) * 4;
            float x;
            x = gr_r[q * 4 + 0] + v.x; x = fmaxf(x, 0.2f * x); e[hh] = fmaf(x, aw_r[f0 + 0], e[hh]);
            x = gr_r[q * 4 + 1] + v.y; x = fmaxf(x, 0.2f * x); e[hh] = fmaf(x, aw_r[f0 + 1], e[hh]);
            x = gr_r[q * 4 + 2] + v.z; x = fmaxf(x, 0.2f * x); e[hh] = fmaf(x, aw_r[f0 + 2], e[hh]);
            x = gr_r[q * 4 + 3] + v.w; x = fmaxf(x, 0.2f * x); e[hh] = fmaf(x, aw_r[f0 + 3], e[hh]);
        }
        #pragma unroll
        for (int hh = 0; hh < NH; ++hh)
            e_buf[hh][j] = m != 0 ? e[hh] : -INFINITY;
    }
    __syncthreads();

    // ---- Phase B: masked softmax over j, one wave per head ----
    {
        const int hh = t >> 6;    // wave id == head
        const int l  = t & 63;
        float mx = -INFINITY;
        for (int j = l; j < NN; j += 64) mx = fmaxf(mx, e_buf[hh][j]);
        #pragma unroll
        for (int off = 32; off; off >>= 1) mx = fmaxf(mx, __shfl_xor(mx, off));

        if (mx > -INFINITY) {
            float s = 0.f;
            for (int j = l; j < NN; j += 64) {
                const float p = __expf(e_buf[hh][j] - mx);   // exp(-inf - mx) = 0 for masked
                e_buf[hh][j] = p;
                s += p;
            }
            #pragma unroll
            for (int off = 32; off; off >>= 1) s += __shfl_xor(s, off);
            const float inv = 1.f / s;                       // s >= 1 (max element gives p=1)
            for (int j = l; j < NN; j += 64) e_buf[hh][j] *= inv;
        } else {
            // no neighbors at all: softmax is NaN -> nan_to_num -> 0
            for (int j = l; j < NN; j += 64) e_buf[hh][j] = 0.f;
        }
    }
    __syncthreads();

    // ---- Phase C: out[i,h,f] = sum_j a[i,j,h] * g_r[j,h,f] ----
    {
        const int c  = t & 63;        // output channel = h*16+f
        const int hh = c >> 4;
        const int grp = t >> 6;       // j-quarter handled by this wave
        float acc = 0.f;
        const int j0 = grp * (NN / 4);
        for (int j = j0; j < j0 + NN / 4; ++j)
            acc = fmaf(e_buf[hh][j], g_r[j * OF + c], acc);  // 64 consecutive floats/wave: coalesced
        red[t] = acc;
        __syncthreads();
        if (t < 64)
            out[i * OF + t] = red[t] + red[t + 64] + red[t + 128] + red[t + 192];
    }
}

extern "C" void kernel_launch(void* const* d_in, const int* in_sizes, int n_in,
                              void* d_out, int out_size, void* d_ws, size_t ws_size,
                              hipStream_t stream) {
    const float* h      = (const float*)d_in[0];
    const int*   adj    = (const int*)d_in[1];
    const float* W_l    = (const float*)d_in[2];
    const float* W_r    = (const float*)d_in[3];
    const float* attn_w = (const float*)d_in[4];
    float*       out    = (float*)d_out;

    float* g_l = (float*)d_ws;                  // [NN, OF]
    float* g_r = g_l + (size_t)NN * OF;         // [NN, OF]

    proj_kernel<<<dim3(NN, 2), 64, 0, stream>>>(h, W_l, W_r, g_l, g_r);
    gat_kernel<<<NN, 256, 0, stream>>>(g_l, g_r, adj, attn_w, out);
}